// Round 1
// baseline (16360.728 us; speedup 1.0000x reference)
//
#include <hip/hip_runtime.h>
#include <math.h>

#define BB 2048
#define DD 512
#define CC 128
#define TT 151
#define G3 1536  // 3*D

// ---------------- precompute kernels ----------------

// Transpose W_hh, W_ih -> [k][j] layout; W_proj -> [k][c]
__global__ void k_transpose(const float* __restrict__ Whh, const float* __restrict__ Wih,
                            const float* __restrict__ Wproj,
                            float* __restrict__ WhhT, float* __restrict__ WihT,
                            float* __restrict__ WprojT) {
    int idx = blockIdx.x * 256 + threadIdx.x;
    if (idx < G3 * DD) {
        int j = idx / DD, k = idx - j * DD;   // reading row-major [j][k], coalesced in k
        WhhT[k * G3 + j] = Whh[idx];
        WihT[k * G3 + j] = Wih[idx];
    }
    if (idx < CC * DD) {
        int c = idx / DD, k = idx - c * DD;
        WprojT[k * CC + c] = Wproj[idx];
    }
}

// E[c][j] = b_ih[j] + sum_k embed[c][k]*W_ih[j][k]  for c<128;  E[128][j] = b_ih[j]
__global__ void k_build_E(const float* __restrict__ embed, const float* __restrict__ WihT,
                          const float* __restrict__ b_ih, float* __restrict__ E) {
    __shared__ float emb[16][DD];  // 32 KB
    const int t = threadIdx.x;
    const int j = blockIdx.x * 256 + t;
    const int c0 = blockIdx.y * 16;
    for (int i = 0; i < 16; i++) {
        int c = c0 + i;
        for (int k = t; k < DD; k += 256)
            emb[i][k] = (c < CC) ? embed[c * DD + k] : 0.0f;
    }
    __syncthreads();
    float acc[16];
#pragma unroll
    for (int i = 0; i < 16; i++) acc[i] = 0.0f;
    for (int k = 0; k < DD; k++) {
        float w = WihT[k * G3 + j];
#pragma unroll
        for (int i = 0; i < 16; i++) acc[i] = fmaf(emb[i][k], w, acc[i]);
    }
    float bj = b_ih[j];
    for (int i = 0; i < 16; i++) {
        int c = c0 + i;
        if (c <= CC) E[(size_t)c * G3 + j] = acc[i] + bj;  // row 128 = b_ih (zero embed)
    }
}

// ---------------- main persistent GRU kernel ----------------

__device__ __forceinline__ float sigmoidf_(float x) {
    return 1.0f / (1.0f + expf(-x));
}

__global__ __launch_bounds__(512) void k_gru(
    const float* __restrict__ feat, const float* __restrict__ WhhT,
    const float* __restrict__ WprojT, const float* __restrict__ b_proj,
    const float* __restrict__ b_hh, const float* __restrict__ E,
    float* __restrict__ out) {
    __shared__ __align__(16) float h[8][DD];     // 16 KB, resident hidden state (8 rows)
    __shared__ float plg[4][8][CC];              // 16 KB, partial logits
    __shared__ int tok_s[8];

    float* out_logits = out;                          // [B][C][T]
    float* out_tok = out + (size_t)BB * CC * TT;      // [B][T] as float

    const int t = threadIdx.x;        // 0..511 ; owns hidden dim d = t
    const int row0 = blockIdx.x * 8;

    // h0 = feat rows
    for (int b = 0; b < 8; b++)
        for (int k = t; k < DD; k += 512)
            h[b][k] = feat[(size_t)(row0 + b) * DD + k];
    if (t < 8) tok_s[t] = CC;  // start token -> E row 128 (= b_ih, x0 = 0)
    __syncthreads();

    // per-thread constant biases (d = t)
    const float bhr = b_hh[t];
    const float bhz = b_hh[t + 512];
    const float bhn = b_hh[t + 1024];
    const int lane = t & 63;
    const float bp0 = b_proj[lane];
    const float bp1 = b_proj[lane + 64];

    for (int step = 0; step < TT; step++) {
        // ---- P1: gh[b][j] = h[b][:] . W_hh[j][:]  for j = t, t+512, t+1024
        float acc[8][3];
#pragma unroll
        for (int b = 0; b < 8; b++) {
            acc[b][0] = 0.f; acc[b][1] = 0.f; acc[b][2] = 0.f;
        }
        const float* wp = WhhT + t;
        for (int k = 0; k < DD; k += 4) {
            float4 hv[8];
#pragma unroll
            for (int b = 0; b < 8; b++) hv[b] = *(const float4*)&h[b][k];
#pragma unroll
            for (int kk = 0; kk < 4; kk++) {
                const float* wr = wp + (size_t)(k + kk) * G3;
                float w0 = wr[0], w1 = wr[512], w2 = wr[1024];
#pragma unroll
                for (int b = 0; b < 8; b++) {
                    float hb = ((const float*)&hv[b])[kk];
                    acc[b][0] = fmaf(hb, w0, acc[b][0]);
                    acc[b][1] = fmaf(hb, w1, acc[b][1]);
                    acc[b][2] = fmaf(hb, w2, acc[b][2]);
                }
            }
        }
        __syncthreads();  // all threads done reading old h

        // ---- P2: gates + h update for d = t (this thread owns h[b][t])
#pragma unroll
        for (int b = 0; b < 8; b++) {
            const float* Er = E + (size_t)tok_s[b] * G3 + t;
            float ir = Er[0], iz = Er[512], in_ = Er[1024];
            float r = sigmoidf_(ir + acc[b][0] + bhr);
            float z = sigmoidf_(iz + acc[b][1] + bhz);
            float hn = acc[b][2] + bhn;
            float n = tanhf(in_ + r * hn);
            h[b][t] = (1.f - z) * n + z * h[b][t];
        }
        __syncthreads();  // h_new ready

        // ---- P3a: partial logits. thread -> (c = t&127, quarter q = t>>7)
        {
            const int c = t & (CC - 1);
            const int q = t >> 7;
            float s[8];
#pragma unroll
            for (int b = 0; b < 8; b++) s[b] = 0.f;
            const int kb = q * 128;
            for (int k = kb; k < kb + 128; k += 4) {
                float w0 = WprojT[(k + 0) * CC + c];
                float w1 = WprojT[(k + 1) * CC + c];
                float w2 = WprojT[(k + 2) * CC + c];
                float w3 = WprojT[(k + 3) * CC + c];
#pragma unroll
                for (int b = 0; b < 8; b++) {
                    float4 hb = *(const float4*)&h[b][k];
                    float v = fmaf(hb.x, w0, fmaf(hb.y, w1, fmaf(hb.z, w2, hb.w * w3)));
                    s[b] += v;
                }
            }
#pragma unroll
            for (int b = 0; b < 8; b++) plg[q][b][c] = s[b];
        }
        __syncthreads();

        // ---- P3b: final logits, write-out, argmax. one wave per row b.
        {
            const int b = t >> 6;  // 0..7
            float v0 = plg[0][b][lane] + plg[1][b][lane] + plg[2][b][lane] + plg[3][b][lane] + bp0;
            float v1 = plg[0][b][lane + 64] + plg[1][b][lane + 64] + plg[2][b][lane + 64] +
                       plg[3][b][lane + 64] + bp1;
            size_t obase = ((size_t)(row0 + b) * CC) * TT + step;
            out_logits[obase + (size_t)lane * TT] = v0;
            out_logits[obase + (size_t)(lane + 64) * TT] = v1;
            // first-occurrence argmax: lower index wins ties
            float bv; int bi;
            if (v0 >= v1) { bv = v0; bi = lane; } else { bv = v1; bi = lane + 64; }
#pragma unroll
            for (int off = 32; off > 0; off >>= 1) {
                float ov = __shfl_down(bv, off, 64);
                int oi = __shfl_down(bi, off, 64);
                if (ov > bv || (ov == bv && oi < bi)) { bv = ov; bi = oi; }
            }
            if (lane == 0) {
                tok_s[b] = bi;
                out_tok[(size_t)(row0 + b) * TT + step] = (float)bi;
            }
        }
        __syncthreads();  // tok_s visible; plg safe to overwrite next step
    }
}

// ---------------- launcher ----------------

extern "C" void kernel_launch(void* const* d_in, const int* in_sizes, int n_in,
                              void* d_out, int out_size, void* d_ws, size_t ws_size,
                              hipStream_t stream) {
    const float* feat   = (const float*)d_in[0];
    const float* W_ih   = (const float*)d_in[1];
    const float* W_hh   = (const float*)d_in[2];
    const float* b_ih   = (const float*)d_in[3];
    const float* b_hh   = (const float*)d_in[4];
    const float* W_proj = (const float*)d_in[5];
    const float* b_proj = (const float*)d_in[6];
    const float* embed  = (const float*)d_in[7];
    float* out = (float*)d_out;

    float* ws = (float*)d_ws;
    float* WhhT   = ws;                    // 512*1536 = 786432
    float* WihT   = ws + 786432;           // 786432
    float* WprojT = ws + 1572864;          // 512*128 = 65536
    float* E      = ws + 1638400;          // 129*1536 = 198144  (total ~7.3 MB)

    hipLaunchKernelGGL(k_transpose, dim3(3072), dim3(256), 0, stream,
                       W_hh, W_ih, W_proj, WhhT, WihT, WprojT);
    hipLaunchKernelGGL(k_build_E, dim3(6, 9), dim3(256), 0, stream,
                       embed, WihT, b_ih, E);
    hipLaunchKernelGGL(k_gru, dim3(256), dim3(512), 0, stream,
                       feat, WhhT, WprojT, b_proj, b_hh, E, out);
}

// Round 2
// 13129.143 us; speedup vs baseline: 1.2461x; 1.2461x over previous
//
#include <hip/hip_runtime.h>
#include <math.h>

#define BB 2048
#define DD 512
#define CC 128
#define TT 151
#define G3 1536  // 3*D

// ---------------- precompute kernels ----------------

// WihT[k*G3 + j] = Wih[j*DD + k]  (for E build)
__global__ void k_transpose_wih(const float* __restrict__ Wih, float* __restrict__ WihT) {
    int idx = blockIdx.x * 256 + threadIdx.x;
    if (idx < G3 * DD) {
        int j = idx / DD, k = idx - j * DD;
        WihT[k * G3 + j] = Wih[idx];
    }
}

// Wh4[(k4*3 + g)*512 + jp] = float4{ W_hh[j][4k4 .. 4k4+3] },  j = g*512 + jp
__global__ void k_pack_whh(const float* __restrict__ Whh, float4* __restrict__ Wh4) {
    int idx = blockIdx.x * 256 + threadIdx.x;  // 1536*128
    if (idx >= G3 * 128) return;
    int j = idx >> 7, k4 = idx & 127;
    int g = j >> 9, jp = j & 511;
    float4 v = *(const float4*)&Whh[j * DD + k4 * 4];
    Wh4[(k4 * 3 + g) * 512 + jp] = v;
}

// Wp4[k4*128 + c] = float4{ W_proj[c][4k4 .. 4k4+3] }
__global__ void k_pack_wp(const float* __restrict__ Wproj, float4* __restrict__ Wp4) {
    int idx = blockIdx.x * 256 + threadIdx.x;  // 128*128
    if (idx >= CC * 128) return;
    int c = idx >> 7, k4 = idx & 127;
    float4 v = *(const float4*)&Wproj[c * DD + k4 * 4];
    Wp4[k4 * CC + c] = v;
}

// E[c][j] = b_ih[j] + sum_k embed[c][k]*W_ih[j][k]  for c<128;  E[128][j] = b_ih[j]
__global__ void k_build_E(const float* __restrict__ embed, const float* __restrict__ WihT,
                          const float* __restrict__ b_ih, float* __restrict__ E) {
    __shared__ float emb[16][DD];  // 32 KB
    const int t = threadIdx.x;
    const int j = blockIdx.x * 256 + t;
    const int c0 = blockIdx.y * 16;
    for (int i = 0; i < 16; i++) {
        int c = c0 + i;
        for (int k = t; k < DD; k += 256)
            emb[i][k] = (c < CC) ? embed[c * DD + k] : 0.0f;
    }
    __syncthreads();
    float acc[16];
#pragma unroll
    for (int i = 0; i < 16; i++) acc[i] = 0.0f;
    for (int k = 0; k < DD; k++) {
        float w = WihT[k * G3 + j];
#pragma unroll
        for (int i = 0; i < 16; i++) acc[i] = fmaf(emb[i][k], w, acc[i]);
    }
    float bj = b_ih[j];
    for (int i = 0; i < 16; i++) {
        int c = c0 + i;
        if (c <= CC) E[(size_t)c * G3 + j] = acc[i] + bj;  // row 128 = b_ih (zero embed)
    }
}

// ---------------- main persistent GRU kernel ----------------

__device__ __forceinline__ float fast_sigmoid(float x) {
    return __builtin_amdgcn_rcpf(1.0f + __expf(-x));
}
__device__ __forceinline__ float fast_tanh(float x) {
    x = fminf(10.0f, fmaxf(-10.0f, x));
    float e = __expf(2.0f * x);
    return (e - 1.0f) * __builtin_amdgcn_rcpf(e + 1.0f);
}

__global__ __launch_bounds__(512, 2) void k_gru(
    const float* __restrict__ feat, const float4* __restrict__ Wh4,
    const float4* __restrict__ Wp4, const float* __restrict__ b_proj,
    const float* __restrict__ b_hh, const float* __restrict__ E,
    float* __restrict__ out) {
    __shared__ __align__(16) float h[8][DD];   // 16 KB resident hidden state (8 rows)
    __shared__ float plg[4][8][CC];            // 16 KB partial logits
    __shared__ float lgbuf[8][CC][9];          // 36 KB: 8 steps of logits, +1 pad (bank-free)
    __shared__ int tok_s[8];

    float* out_logits = out;                      // [B][C][T]
    float* out_tok = out + (size_t)BB * CC * TT;  // [B][T] as float

    const int t = threadIdx.x;  // 0..511, owns hidden dim d = t
    const int row0 = blockIdx.x * 8;

    for (int b = 0; b < 8; b++)
        h[b][t] = feat[(size_t)(row0 + b) * DD + t];
    if (t < 8) tok_s[t] = CC;  // start token -> E row 128 (x0 = 0)
    __syncthreads();

    const float bhr = b_hh[t];
    const float bhz = b_hh[t + 512];
    const float bhn = b_hh[t + 1024];
    const int lane = t & 63;
    const float bp0 = b_proj[lane];
    const float bp1 = b_proj[lane + 64];

    for (int step = 0; step < TT; step++) {
        // ---- P1: gh[b][j] = h[b][:] . W_hh[j][:]  for j = t, t+512, t+1024
        float acc[8][3];
#pragma unroll
        for (int b = 0; b < 8; b++) {
            acc[b][0] = 0.f; acc[b][1] = 0.f; acc[b][2] = 0.f;
        }
        const float4* wp = Wh4 + t;
#pragma unroll 4
        for (int k4 = 0; k4 < 128; k4++) {
            float4 wr = wp[(k4 * 3 + 0) * 512];
            float4 wz = wp[(k4 * 3 + 1) * 512];
            float4 wn = wp[(k4 * 3 + 2) * 512];
#pragma unroll
            for (int b = 0; b < 8; b++) {
                float4 hv = *(const float4*)&h[b][k4 * 4];
                acc[b][0] = fmaf(hv.x, wr.x, fmaf(hv.y, wr.y, fmaf(hv.z, wr.z, fmaf(hv.w, wr.w, acc[b][0]))));
                acc[b][1] = fmaf(hv.x, wz.x, fmaf(hv.y, wz.y, fmaf(hv.z, wz.z, fmaf(hv.w, wz.w, acc[b][1]))));
                acc[b][2] = fmaf(hv.x, wn.x, fmaf(hv.y, wn.y, fmaf(hv.z, wn.z, fmaf(hv.w, wn.w, acc[b][2]))));
            }
        }
        __syncthreads();  // all threads done reading old h

        // ---- P2: gates + h update for d = t
#pragma unroll
        for (int b = 0; b < 8; b++) {
            const float* Er = E + (size_t)tok_s[b] * G3 + t;
            float ir = Er[0], iz = Er[512], in_ = Er[1024];
            float r = fast_sigmoid(ir + acc[b][0] + bhr);
            float z = fast_sigmoid(iz + acc[b][1] + bhz);
            float n = fast_tanh(in_ + r * (acc[b][2] + bhn));
            h[b][t] = (1.f - z) * n + z * h[b][t];
        }
        __syncthreads();  // h_new ready

        // ---- P3a: partial logits; thread -> (c = t&127, quarter q = t>>7)
        {
            const int c = t & (CC - 1);
            const int q = t >> 7;
            float s[8];
#pragma unroll
            for (int b = 0; b < 8; b++) s[b] = 0.f;
            const int kb4 = q * 32;
#pragma unroll 4
            for (int k4 = 0; k4 < 32; k4++) {
                float4 w = Wp4[(kb4 + k4) * CC + c];
#pragma unroll
                for (int b = 0; b < 8; b++) {
                    float4 hv = *(const float4*)&h[b][(kb4 + k4) * 4];
                    s[b] = fmaf(hv.x, w.x, fmaf(hv.y, w.y, fmaf(hv.z, w.z, fmaf(hv.w, w.w, s[b]))));
                }
            }
#pragma unroll
            for (int b = 0; b < 8; b++) plg[q][b][c] = s[b];
        }
        __syncthreads();

        // ---- P3b: final logits -> LDS buffer, argmax. one wave per row b.
        {
            const int b = t >> 6;
            float v0 = plg[0][b][lane] + plg[1][b][lane] + plg[2][b][lane] + plg[3][b][lane] + bp0;
            float v1 = plg[0][b][lane + 64] + plg[1][b][lane + 64] + plg[2][b][lane + 64] +
                       plg[3][b][lane + 64] + bp1;
            const int sl = step & 7;
            lgbuf[b][lane][sl] = v0;
            lgbuf[b][lane + 64][sl] = v1;
            // first-occurrence argmax: lower index wins ties
            float bv; int bi;
            if (v0 >= v1) { bv = v0; bi = lane; } else { bv = v1; bi = lane + 64; }
#pragma unroll
            for (int off = 32; off > 0; off >>= 1) {
                float ov = __shfl_down(bv, off, 64);
                int oi = __shfl_down(bi, off, 64);
                if (ov > bv || (ov == bv && oi < bi)) { bv = ov; bi = oi; }
            }
            if (lane == 0) {
                tok_s[b] = bi;
                out_tok[(size_t)(row0 + b) * TT + step] = (float)bi;
            }
        }
        __syncthreads();  // tok_s + lgbuf visible

        // ---- flush logits buffer every 8 steps (burst writes merge in L2)
        if ((step & 7) == 7 || step == TT - 1) {
            const int t0 = step & ~7;
            const int cnt = step - t0 + 1;
#pragma unroll
            for (int p = 0; p < 2; p++) {
                const int pair = t + p * 512;
                const int b = pair >> 7, c = pair & (CC - 1);
                float* dst = out_logits + ((size_t)(row0 + b) * CC + c) * TT + t0;
                const float* src = &lgbuf[b][c][0];
                for (int s = 0; s < cnt; s++) dst[s] = src[s];
            }
        }
    }
}

// ---------------- launcher ----------------

extern "C" void kernel_launch(void* const* d_in, const int* in_sizes, int n_in,
                              void* d_out, int out_size, void* d_ws, size_t ws_size,
                              hipStream_t stream) {
    const float* feat   = (const float*)d_in[0];
    const float* W_ih   = (const float*)d_in[1];
    const float* W_hh   = (const float*)d_in[2];
    const float* b_ih   = (const float*)d_in[3];
    const float* b_hh   = (const float*)d_in[4];
    const float* W_proj = (const float*)d_in[5];
    const float* b_proj = (const float*)d_in[6];
    const float* embed  = (const float*)d_in[7];
    float* out = (float*)d_out;

    float* ws = (float*)d_ws;
    float*  WihT = ws;                        // 786432 floats
    float4* Wh4  = (float4*)(ws + 786432);    // 196608 float4 = 786432 floats
    float4* Wp4  = (float4*)(ws + 1572864);   // 16384 float4 = 65536 floats
    float*  E    = ws + 1638400;              // 129*1536 = 198144 floats

    hipLaunchKernelGGL(k_transpose_wih, dim3(3072), dim3(256), 0, stream, W_ih, WihT);
    hipLaunchKernelGGL(k_pack_whh, dim3(768), dim3(256), 0, stream, W_hh, Wh4);
    hipLaunchKernelGGL(k_pack_wp, dim3(64), dim3(256), 0, stream, W_proj, Wp4);
    hipLaunchKernelGGL(k_build_E, dim3(6, 9), dim3(256), 0, stream, embed, WihT, b_ih, E);
    hipLaunchKernelGGL(k_gru, dim3(256), dim3(512), 0, stream,
                       feat, Wh4, Wp4, b_proj, b_hh, E, out);
}

// Round 3
// 6325.644 us; speedup vs baseline: 2.5864x; 2.0755x over previous
//
#include <hip/hip_runtime.h>
#include <math.h>

#define BB 2048
#define DD 512
#define CC 128
#define TT 151
#define G3 1536  // 3*D

typedef __bf16 bf16x8 __attribute__((ext_vector_type(8)));
typedef float f32x4 __attribute__((ext_vector_type(4)));

// ---------------- precompute kernels ----------------

// WihT[k*G3 + j] = Wih[j*DD + k]  (for E build)
__global__ void k_transpose_wih(const float* __restrict__ Wih, float* __restrict__ WihT) {
    int idx = blockIdx.x * 256 + threadIdx.x;
    if (idx < G3 * DD) {
        int j = idx / DD, k = idx - j * DD;
        WihT[k * G3 + j] = Wih[idx];
    }
}

// Wp4[k4*128 + c] = float4{ W_proj[c][4k4 .. 4k4+3] }   (fp32 projection weights)
__global__ void k_pack_wp(const float* __restrict__ Wproj, float4* __restrict__ Wp4) {
    int idx = blockIdx.x * 256 + threadIdx.x;  // 128*128
    if (idx >= CC * 128) return;
    int c = idx >> 7, k4 = idx & 127;
    float4 v = *(const float4*)&Wproj[c * DD + k4 * 4];
    Wp4[k4 * CC + c] = v;
}

// Pack W_hh into split-bf16 B-fragments in per-wave streaming order.
// Layout: [w 0..7][kt 0..15][tile 0..11][part hi/lo][lane 0..63][j 0..7]  (bf16)
// tile: 0..3 -> r-gate, 4..7 -> z, 8..11 -> n.  For wave w, tile t (local tl=t&3):
//   jcol = (t>>2)*512 + w*64 + tl*16 + (lane&15),  k = kt*32 + (lane>>4)*8 + j
//   value = W_hh[jcol][k]
__global__ void k_pack_whh_frag(const float* __restrict__ Whh, __bf16* __restrict__ out) {
    int idx = blockIdx.x * 256 + threadIdx.x;  // 8*16*12*512 = 786432
    if (idx >= 786432) return;
    int j8 = idx & 7;
    int lane = (idx >> 3) & 63;
    int rest = idx >> 9;          // 0..1535 = tile + 12*(kt + 16*w)
    int tile = rest % 12;
    int kt = (rest / 12) % 16;
    int w = rest / (12 * 16);
    int g = tile >> 2, tl = tile & 3;
    int col = lane & 15, quad = lane >> 4;
    int jcol = g * 512 + w * 64 + tl * 16 + col;
    int k = kt * 32 + quad * 8 + j8;
    float v = Whh[jcol * DD + k];
    __bf16 hi = (__bf16)v;
    __bf16 lo = (__bf16)(v - (float)hi);
    size_t base = ((((size_t)w * 16 + kt) * 12 + tile) * 2) * 512 + lane * 8 + j8;
    out[base] = hi;
    out[base + 512] = lo;
}

// E[c][j] = b_ih[j] + (j<1024 ? b_hh[j] : 0) + sum_k embed[c][k]*W_ih[j][k]; row 128 = biases only
// (b_hh for r,z gates folded in; b_hh_n must stay inside the r-multiply -> not folded)
__global__ void k_build_E(const float* __restrict__ embed, const float* __restrict__ WihT,
                          const float* __restrict__ b_ih, const float* __restrict__ b_hh,
                          float* __restrict__ E) {
    __shared__ float emb[16][DD];
    const int t = threadIdx.x;
    const int j = blockIdx.x * 256 + t;
    const int c0 = blockIdx.y * 16;
    for (int i = 0; i < 16; i++) {
        int c = c0 + i;
        for (int k = t; k < DD; k += 256)
            emb[i][k] = (c < CC) ? embed[c * DD + k] : 0.0f;
    }
    __syncthreads();
    float acc[16];
#pragma unroll
    for (int i = 0; i < 16; i++) acc[i] = 0.0f;
    for (int k = 0; k < DD; k++) {
        float w = WihT[k * G3 + j];
#pragma unroll
        for (int i = 0; i < 16; i++) acc[i] = fmaf(emb[i][k], w, acc[i]);
    }
    float bj = b_ih[j] + (j < 1024 ? b_hh[j] : 0.0f);
    for (int i = 0; i < 16; i++) {
        int c = c0 + i;
        if (c <= CC) E[(size_t)c * G3 + j] = acc[i] + bj;
    }
}

// ---------------- main persistent GRU kernel ----------------

__device__ __forceinline__ float fast_sigmoid(float x) {
    return __builtin_amdgcn_rcpf(1.0f + __expf(-x));
}
__device__ __forceinline__ float fast_tanh(float x) {
    x = fminf(10.0f, fmaxf(-10.0f, x));
    float e = __expf(2.0f * x);
    return (e - 1.0f) * __builtin_amdgcn_rcpf(e + 1.0f);
}

__global__ __launch_bounds__(512, 2) void k_gru(
    const float* __restrict__ feat, const __bf16* __restrict__ Whf,
    const float4* __restrict__ Wp4, const float* __restrict__ b_proj,
    const float* __restrict__ b_hh, const float* __restrict__ Ep,
    float* __restrict__ out) {
    __shared__ __align__(16) float h[8][DD];       // 16 KB fp32 hidden (for projection)
    __shared__ __align__(16) __bf16 h_hi[16][520]; // 16.25 KB, rows 8..15 zero (M-pad), +8 pad
    __shared__ __align__(16) __bf16 h_lo[16][520]; // 16.25 KB
    __shared__ float plg[4][8][CC];                // 16 KB partial logits
    __shared__ float lgbuf[8][CC][9];              // 36 KB logit burst buffer
    __shared__ int tok_s[8];

    float* out_logits = out;                      // [B][C][T]
    float* out_tok = out + (size_t)BB * CC * TT;  // [B][T] as float

    const int t = threadIdx.x;   // 0..511
    const int w = t >> 6;        // wave 0..7: owns d in [64w, 64w+64)
    const int lane = t & 63;
    const int row0 = blockIdx.x * 8;

    // zero bf16 h arrays (incl. pad rows 8..15 and column pad)
    for (int i = t; i < 16 * 520; i += 512) {
        ((__bf16*)h_hi)[i] = (__bf16)0.0f;
        ((__bf16*)h_lo)[i] = (__bf16)0.0f;
    }
    __syncthreads();
    for (int b = 0; b < 8; b++) {
        float v = feat[(size_t)(row0 + b) * DD + t];
        h[b][t] = v;
        __bf16 hi = (__bf16)v;
        h_hi[b][t] = hi;
        h_lo[b][t] = (__bf16)(v - (float)hi);
    }
    if (t < 8) tok_s[t] = CC;  // start token -> E row 128 (x0 = 0)
    __syncthreads();

    // per-lane constants
    const float bp0 = b_proj[lane];
    const float bp1 = b_proj[lane + 64];
    float bhn_t[4];
#pragma unroll
    for (int tile = 0; tile < 4; tile++)
        bhn_t[tile] = b_hh[1024 + w * 64 + tile * 16 + (lane & 15)];

    const __bf16* wseq = Whf + (size_t)w * 196608;  // per-wave weight stream
    const int am = lane & 15, aq = lane >> 4;

    for (int step = 0; step < TT; step++) {
        // ---- P1: gh = h @ W_hh^T via split-bf16 MFMA (M=16: 8 rows + 8 pad)
        f32x4 acc[12];
#pragma unroll
        for (int i = 0; i < 12; i++) acc[i] = (f32x4)(0.0f);
        for (int kt = 0; kt < 16; kt++) {
            bf16x8 ahi = *(const bf16x8*)&h_hi[am][kt * 32 + aq * 8];
            bf16x8 alo = *(const bf16x8*)&h_lo[am][kt * 32 + aq * 8];
            const __bf16* wk = wseq + kt * 12288;
#pragma unroll
            for (int tile = 0; tile < 12; tile++) {
                bf16x8 bhi = *(const bf16x8*)(wk + tile * 1024 + lane * 8);
                bf16x8 blo = *(const bf16x8*)(wk + tile * 1024 + 512 + lane * 8);
                acc[tile] = __builtin_amdgcn_mfma_f32_16x16x32_bf16(ahi, bhi, acc[tile], 0, 0, 0);
                acc[tile] = __builtin_amdgcn_mfma_f32_16x16x32_bf16(alo, bhi, acc[tile], 0, 0, 0);
                acc[tile] = __builtin_amdgcn_mfma_f32_16x16x32_bf16(ahi, blo, acc[tile], 0, 0, 0);
            }
        }
        __syncthreads();  // all waves done reading h_hi/h_lo

        // ---- P2: gates entirely in registers; D-frag row=(lane>>4)*4+reg, col=lane&15
        if (lane < 32) {
            const int dcol = lane & 15;
            const int bq = (lane >> 4) * 4;
#pragma unroll
            for (int tile = 0; tile < 4; tile++) {
                const int d = w * 64 + tile * 16 + dcol;
#pragma unroll
                for (int rg = 0; rg < 4; rg++) {
                    const int b = bq + rg;
                    const float* Er = Ep + (size_t)tok_s[b] * G3 + d;
                    float rr = fast_sigmoid(acc[tile][rg] + Er[0]);        // E has b_ih+b_hh(r)
                    float zz = fast_sigmoid(acc[4 + tile][rg] + Er[512]);  // E has b_ih+b_hh(z)
                    float nn = fast_tanh(Er[1024] + rr * (acc[8 + tile][rg] + bhn_t[tile]));
                    float ho = h[b][d];
                    float hv = (1.0f - zz) * nn + zz * ho;
                    h[b][d] = hv;
                    __bf16 hi = (__bf16)hv;
                    h_hi[b][d] = hi;
                    h_lo[b][d] = (__bf16)(hv - (float)hi);
                }
            }
        }
        __syncthreads();  // h_new ready

        // ---- P3a: partial logits (fp32 VALU); thread -> (c = t&127, quarter q = t>>7)
        {
            const int c = t & (CC - 1);
            const int q = t >> 7;
            float s[8];
#pragma unroll
            for (int b = 0; b < 8; b++) s[b] = 0.f;
            const int kb4 = q * 32;
#pragma unroll 4
            for (int k4 = 0; k4 < 32; k4++) {
                float4 wv = Wp4[(kb4 + k4) * CC + c];
#pragma unroll
                for (int b = 0; b < 8; b++) {
                    float4 hv = *(const float4*)&h[b][(kb4 + k4) * 4];
                    s[b] = fmaf(hv.x, wv.x, fmaf(hv.y, wv.y, fmaf(hv.z, wv.z, fmaf(hv.w, wv.w, s[b]))));
                }
            }
#pragma unroll
            for (int b = 0; b < 8; b++) plg[q][b][c] = s[b];
        }
        __syncthreads();

        // ---- P3b: final logits -> LDS buffer, argmax. one wave per row b.
        {
            const int b = w;
            float v0 = plg[0][b][lane] + plg[1][b][lane] + plg[2][b][lane] + plg[3][b][lane] + bp0;
            float v1 = plg[0][b][lane + 64] + plg[1][b][lane + 64] + plg[2][b][lane + 64] +
                       plg[3][b][lane + 64] + bp1;
            const int sl = step & 7;
            lgbuf[b][lane][sl] = v0;
            lgbuf[b][lane + 64][sl] = v1;
            float bv; int bi;
            if (v0 >= v1) { bv = v0; bi = lane; } else { bv = v1; bi = lane + 64; }
#pragma unroll
            for (int off = 32; off > 0; off >>= 1) {
                float ov = __shfl_down(bv, off, 64);
                int oi = __shfl_down(bi, off, 64);
                if (ov > bv || (ov == bv && oi < bi)) { bv = ov; bi = oi; }
            }
            if (lane == 0) {
                tok_s[b] = bi;
                __builtin_nontemporal_store((float)bi, &out_tok[(size_t)(row0 + b) * TT + step]);
            }
        }
        __syncthreads();  // tok_s + lgbuf visible

        // ---- flush logits buffer every 8 steps (nontemporal: keep weights L2-resident)
        if ((step & 7) == 7 || step == TT - 1) {
            const int t0 = step & ~7;
            const int cnt = step - t0 + 1;
#pragma unroll
            for (int p = 0; p < 2; p++) {
                const int pair = t + p * 512;
                const int b = pair >> 7, c = pair & (CC - 1);
                float* dst = out_logits + ((size_t)(row0 + b) * CC + c) * TT + t0;
                const float* src = &lgbuf[b][c][0];
                for (int s = 0; s < cnt; s++) __builtin_nontemporal_store(src[s], &dst[s]);
            }
        }
    }
}

// ---------------- launcher ----------------

extern "C" void kernel_launch(void* const* d_in, const int* in_sizes, int n_in,
                              void* d_out, int out_size, void* d_ws, size_t ws_size,
                              hipStream_t stream) {
    const float* feat   = (const float*)d_in[0];
    const float* W_ih   = (const float*)d_in[1];
    const float* W_hh   = (const float*)d_in[2];
    const float* b_ih   = (const float*)d_in[3];
    const float* b_hh   = (const float*)d_in[4];
    const float* W_proj = (const float*)d_in[5];
    const float* b_proj = (const float*)d_in[6];
    const float* embed  = (const float*)d_in[7];
    float* out = (float*)d_out;

    float* ws = (float*)d_ws;
    float*  WihT = ws;                         // 786432 floats
    float*  E    = ws + 786432;                // 198144 floats
    float4* Wp4  = (float4*)(ws + 984576);     // 65536 floats
    __bf16* Whf  = (__bf16*)(ws + 1050112);    // 1572864 bf16 = 786432 float slots
    // total: 1836544 floats = 7.3 MB

    hipLaunchKernelGGL(k_transpose_wih, dim3(3072), dim3(256), 0, stream, W_ih, WihT);
    hipLaunchKernelGGL(k_pack_wp, dim3(64), dim3(256), 0, stream, W_proj, Wp4);
    hipLaunchKernelGGL(k_pack_whh_frag, dim3(3072), dim3(256), 0, stream, W_hh, Whf);
    hipLaunchKernelGGL(k_build_E, dim3(6, 9), dim3(256), 0, stream, embed, WihT, b_ih, b_hh, E);
    hipLaunchKernelGGL(k_gru, dim3(256), dim3(512), 0, stream,
                       feat, Whf, Wp4, b_proj, b_hh, E, out);
}